// Round 5
// baseline (123.900 us; speedup 1.0000x reference)
//
#include <hip/hip_runtime.h>
#include <hip/hip_bf16.h>

#define HEADS 16
#define B_    8
#define H_    2048
#define L_    1024
#define DK    128   // H_/HEADS

typedef __attribute__((ext_vector_type(8))) __bf16 bf16x8;
typedef __attribute__((ext_vector_type(4))) float  f32x4;

// async global->LDS, 16 B per lane, lane-linear LDS dest (HW: base + lane*16)
__device__ __forceinline__ void gload_lds16(const void* g, void* l) {
  __builtin_amdgcn_global_load_lds(
      (const __attribute__((address_space(1))) void*)g,
      (__attribute__((address_space(3))) void*)l, 16, 0, 0);
}

// ---------------------------------------------------------------------------
// Kernel 0a: qwb[bh][j] = sum_d q[b, head*DK+d] * Wq[d][j] + bias[j]
// ---------------------------------------------------------------------------
__global__ void __launch_bounds__(256)
prep_qwb_kernel(const float* __restrict__ query,
                const float* __restrict__ attn_w,
                const float* __restrict__ bias,
                float* __restrict__ qwb) {
  const int jt  = blockIdx.x;   // 0..7
  const int bg  = blockIdx.y;   // 0..15
  const int tid = threadIdx.x;
  __shared__ float qv[8][DK];
  for (int i = tid; i < 8 * DK; i += 256) {
    const int bh = bg * 8 + (i >> 7);
    const int d  = i & 127;
    const int b = bh >> 4, head = bh & 15;
    qv[i >> 7][d] = query[b * H_ + head * DK + d];
  }
  __syncthreads();
  const int j = jt * 256 + tid;
  const float bj = bias[j];
  float acc[8];
#pragma unroll
  for (int u = 0; u < 8; ++u) acc[u] = bj;
  for (int d = 0; d < DK; ++d) {
    const float wv = attn_w[d * H_ + j];
#pragma unroll
    for (int u = 0; u < 8; ++u) acc[u] += qv[u][d] * wv;
  }
#pragma unroll
  for (int u = 0; u < 8; ++u) qwb[(size_t)(bg * 8 + u) * H_ + j] = acc[u];
}

// ---------------------------------------------------------------------------
// Kernel 0b: Wk -> bf16 in MFMA fragment order:
// wktf[((nc*4+ks)*64 + lane)*8 + i] = Wk[k][n],
//   n = nc*16 + (lane&15), k = ks*32 + (lane>>4)*8 + i
// ---------------------------------------------------------------------------
__global__ void prep_wktf_kernel(const float* __restrict__ attn_w,
                                 __bf16* __restrict__ wktf) {
  const int t = blockIdx.x * blockDim.x + threadIdx.x;   // 0..32767
  const int lane  = t & 63;
  const int chunk = t >> 6;          // nc*4 + ks
  const int ks = chunk & 3;
  const int nc = chunk >> 2;
  const int row = lane & 15, g = lane >> 4;
  const int n  = nc * 16 + row;
  const int k0 = ks * 32 + g * 8;
  bf16x8 v;
#pragma unroll
  for (int i = 0; i < 8; ++i)
    v[i] = (__bf16)attn_w[(size_t)(DK + k0 + i) * H_ + n];
  *(bf16x8*)(wktf + (size_t)t * 8) = v;
}

// ---------------------------------------------------------------------------
// Kernel 1: logits[bh][l] = sum_n relu( (K Wk)[l][n] + qwb[bh][n] ) * score[n]
// Block = 4 waves x 64 rows = 256 rows of one bh. A resident in registers.
// Each wave processes ALL 128 n-chunks for its rows, staging B through a
// PRIVATE 4-slot LDS ring via global_load_lds, prefetch depth 2, counted
// s_waitcnt vmcnt(8) — no barriers in the main loop.
// ---------------------------------------------------------------------------
__global__ void __launch_bounds__(256, 2)
logits_kernel(const float* __restrict__ feed,
              const __bf16* __restrict__ wktf,
              const float* __restrict__ qwb,
              const float* __restrict__ score,
              float* __restrict__ logits) {
  const int ltile = blockIdx.x;     // 0..3 (256 rows each)
  const int bh    = blockIdx.y;     // 0..127
  const int b     = bh >> 4;
  const int head  = bh & 15;
  const int tid   = threadIdx.x;
  const int wave  = tid >> 6;
  const int lane  = tid & 63;
  const int row   = lane & 15;      // A row / B col / D col
  const int g     = lane >> 4;      // k-group 0..3

  __shared__ bf16x8 ring[4][4][256];   // [wave][slot][ks*64+lane]: 64 KB
  __shared__ float2 qs[H_];            // {qwb[bh][n], score[n]}: 16 KB

  // ---- stage qs (block-cooperative) ----
#pragma unroll
  for (int u = 0; u < 8; ++u) {
    const int n = tid + 256 * u;
    float2 t;
    t.x = qwb[(size_t)bh * H_ + n];
    t.y = score[n];
    qs[n] = t;
  }

  // ---- A fragments: 4 subtiles x 4 k-steps, resident in registers ----
  bf16x8 aF[4][4];
#pragma unroll
  for (int s = 0; s < 4; ++s) {
    const int l = ltile * 256 + wave * 64 + s * 16 + row;
    const float* fh = feed + (size_t)l * (B_ * H_) + b * H_ + head * DK;
#pragma unroll
    for (int ks = 0; ks < 4; ++ks) {
      const int k0 = ks * 32 + g * 8;
      float4 x = *(const float4*)(fh + k0);
      float4 y = *(const float4*)(fh + k0 + 4);
      bf16x8 t;
      t[0] = (__bf16)x.x; t[1] = (__bf16)x.y; t[2] = (__bf16)x.z; t[3] = (__bf16)x.w;
      t[4] = (__bf16)y.x; t[5] = (__bf16)y.y; t[6] = (__bf16)y.z; t[7] = (__bf16)y.w;
      aF[s][ks] = t;
    }
  }
  __syncthreads();   // qs visible; also drains all prologue register loads

  // ---- issue ring prologue: chunks 0 and 1 ----
  const char* wkb   = (const char*)wktf;
  const char* gsrc  = wkb + lane * 16;   // per-lane source base
#pragma unroll
  for (int c = 0; c < 2; ++c) {
#pragma unroll
    for (int ks = 0; ks < 4; ++ks)
      gload_lds16(gsrc + c * 4096 + ks * 1024, &ring[wave][c][ks * 64]);
  }

  float lacc[4][4] = {};

  for (int nc = 0; nc < 128; ++nc) {
    // issue prefetch for chunk nc+2 (clamped; redundant tail loads land in
    // slots that are never read again)
    const int pf = (nc + 2 < 128) ? nc + 2 : 127;
    const int ps = (nc + 2) & 3;
#pragma unroll
    for (int ks = 0; ks < 4; ++ks)
      gload_lds16(gsrc + (size_t)pf * 4096 + ks * 1024, &ring[wave][ps][ks * 64]);

    // wait for chunk nc's 4 loads (leave 8 in flight: chunks nc+1, nc+2)
    asm volatile("s_waitcnt vmcnt(8)" ::: "memory");
    __builtin_amdgcn_sched_barrier(0);

    const int slot = nc & 3;
    bf16x8 bF[4];
#pragma unroll
    for (int ks = 0; ks < 4; ++ks)
      bF[ks] = ring[wave][slot][ks * 64 + lane];
    const float2 q2 = qs[nc * 16 + row];
    f32x4 d[4];
#pragma unroll
    for (int s = 0; s < 4; ++s) d[s] = (f32x4){q2.x, q2.x, q2.x, q2.x};
#pragma unroll
    for (int ks = 0; ks < 4; ++ks) {
#pragma unroll
      for (int s = 0; s < 4; ++s)
        d[s] = __builtin_amdgcn_mfma_f32_16x16x32_bf16(aF[s][ks], bF[ks], d[s], 0, 0, 0);
    }
#pragma unroll
    for (int s = 0; s < 4; ++s) {
#pragma unroll
      for (int i = 0; i < 4; ++i)
        lacc[s][i] += fmaxf(d[s][i], 0.f) * q2.y;
    }
  }

  // ---- reduce over the 16 D-columns, write logits ----
#pragma unroll
  for (int s = 0; s < 4; ++s) {
#pragma unroll
    for (int i = 0; i < 4; ++i) {
      float v = lacc[s][i];
#pragma unroll
      for (int off = 1; off < 16; off <<= 1) v += __shfl_xor(v, off);
      lacc[s][i] = v;
    }
  }
  if (row == 0) {
#pragma unroll
    for (int s = 0; s < 4; ++s) {
      const int base = bh * L_ + ltile * 256 + wave * 64 + s * 16 + g * 4;
#pragma unroll
      for (int i = 0; i < 4; ++i) logits[base + i] = lacc[s][i];
    }
  }
}

// ---------------------------------------------------------------------------
// Kernel 2: grid (bh, dpart): softmax over L (redundant per dpart, cheap),
// then out[d] over this block's 32 d-columns. values read as float4.
// ---------------------------------------------------------------------------
__global__ void __launch_bounds__(256)
softmax_pv_kernel(const float* __restrict__ logits,
                  const float* __restrict__ values,
                  float* __restrict__ out) {
  const int bh    = blockIdx.x;   // 0..127
  const int dpart = blockIdx.y;   // 0..3  (32 d-cols each)
  const int b     = bh >> 4;
  const int head  = bh & 15;
  const int tid   = threadIdx.x;

  __shared__ float  sl[L_];
  __shared__ float  sred[4];
  __shared__ float  sscal;
  __shared__ float4 pacc[32][8];

  float m = -1e30f;
  for (int i = tid; i < L_; i += 256) {
    float v = logits[(size_t)bh * L_ + i];
    sl[i] = v;
    m = fmaxf(m, v);
  }
#pragma unroll
  for (int off = 32; off > 0; off >>= 1) m = fmaxf(m, __shfl_xor(m, off));
  if ((tid & 63) == 0) sred[tid >> 6] = m;
  __syncthreads();
  if (tid == 0) {
    float mm = fmaxf(fmaxf(sred[0], sred[1]), fmaxf(sred[2], sred[3]));
    sscal = mm;
  }
  __syncthreads();
  const float mx = sscal;

  float s = 0.f;
  for (int i = tid; i < L_; i += 256) {
    float e = __expf(sl[i] - mx);
    sl[i] = e;
    s += e;
  }
#pragma unroll
  for (int off = 32; off > 0; off >>= 1) s += __shfl_xor(s, off);
  if ((tid & 63) == 0) sred[tid >> 6] = s;
  __syncthreads();
  if (tid == 0) {
    sscal = 1.0f / ((sred[0] + sred[1]) + (sred[2] + sred[3]));
  }
  __syncthreads();
  const float inv = sscal;

  // PV over 32 cols: 8 float4-cols x 32 l-subsets
  const int dq4  = tid & 7;
  const int lsub = tid >> 3;
  const float4* vp = (const float4*)(values + (size_t)b * H_ + head * DK + dpart * 32) + dq4;
  float4 acc = {0.f, 0.f, 0.f, 0.f};
  for (int ll = lsub; ll < L_; ll += 32) {
    const float w = sl[ll];
    float4 v = vp[(size_t)ll * (B_ * H_ / 4)];
    acc.x += w * v.x; acc.y += w * v.y; acc.z += w * v.z; acc.w += w * v.w;
  }
  pacc[lsub][dq4] = acc;
  __syncthreads();
  if (tid < 64) {
    const int q = tid & 7, k = tid >> 3;
    float4 a0 = pacc[k][q], a1 = pacc[k + 8][q], a2 = pacc[k + 16][q], a3 = pacc[k + 24][q];
    float4 r;
    r.x = (a0.x + a1.x) + (a2.x + a3.x);
    r.y = (a0.y + a1.y) + (a2.y + a3.y);
    r.z = (a0.z + a1.z) + (a2.z + a3.z);
    r.w = (a0.w + a1.w) + (a2.w + a3.w);
    pacc[k][q] = r;
  }
  __syncthreads();
  if (tid < 8) {
    float4 t = {0.f, 0.f, 0.f, 0.f};
#pragma unroll
    for (int k = 0; k < 8; ++k) {
      float4 a = pacc[k][tid];
      t.x += a.x; t.y += a.y; t.z += a.z; t.w += a.w;
    }
    t.x *= inv; t.y *= inv; t.z *= inv; t.w *= inv;
    *(float4*)(out + (size_t)b * H_ + head * DK + dpart * 32 + tid * 4) = t;
  }
}

// ---------------------------------------------------------------------------
extern "C" void kernel_launch(void* const* d_in, const int* in_sizes, int n_in,
                              void* d_out, int out_size, void* d_ws, size_t ws_size,
                              hipStream_t stream) {
  const float* query  = (const float*)d_in[0];
  const float* feed   = (const float*)d_in[1];
  const float* values = (const float*)d_in[2];
  const float* attn_w = (const float*)d_in[3];
  const float* bias   = (const float*)d_in[4];
  const float* score  = (const float*)d_in[5];
  float* out = (float*)d_out;

  // Workspace: qwb (1 MB f32) | wktf (512 KB bf16) | logits (512 KB f32)
  float*  qwb    = (float*)d_ws;
  __bf16* wktf   = (__bf16*)((char*)d_ws + (size_t)(B_ * HEADS * H_) * sizeof(float));
  float*  logits = (float*)((char*)wktf + (size_t)(H_ * DK) * sizeof(__bf16));

  prep_qwb_kernel<<<dim3(H_ / 256, B_ * HEADS / 8), 256, 0, stream>>>(query, attn_w, bias, qwb);
  prep_wktf_kernel<<<(H_ * DK / 8) / 256, 256, 0, stream>>>(attn_w, wktf);
  logits_kernel<<<dim3(L_ / 256, B_ * HEADS), 256, 0, stream>>>(feed, wktf, qwb, score, logits);
  softmax_pv_kernel<<<dim3(B_ * HEADS, 4), 256, 0, stream>>>(logits, values, out);
}

// Round 6
// 101.349 us; speedup vs baseline: 1.2225x; 1.2225x over previous
//
#include <hip/hip_runtime.h>
#include <hip/hip_bf16.h>

#define HEADS 16
#define B_    8
#define H_    2048
#define L_    1024
#define DK    128   // H_/HEADS

typedef __attribute__((ext_vector_type(8))) __bf16 bf16x8;
typedef __attribute__((ext_vector_type(4))) float  f32x4;

// async global->LDS, 16 B per lane: global src is per-lane, LDS dest is
// wave-uniform base (HW adds lane*16)
__device__ __forceinline__ void gload_lds16(const void* g, void* l) {
  __builtin_amdgcn_global_load_lds(
      (const __attribute__((address_space(1))) void*)g,
      (__attribute__((address_space(3))) void*)l, 16, 0, 0);
}

// ---------------------------------------------------------------------------
// Kernel 0a: qwb[bh][j] = sum_d q[b, head*DK+d] * Wq[d][j] + bias[j]
// ---------------------------------------------------------------------------
__global__ void __launch_bounds__(256)
prep_qwb_kernel(const float* __restrict__ query,
                const float* __restrict__ attn_w,
                const float* __restrict__ bias,
                float* __restrict__ qwb) {
  const int jt  = blockIdx.x;   // 0..7
  const int bg  = blockIdx.y;   // 0..15
  const int tid = threadIdx.x;
  __shared__ float qv[8][DK];
  for (int i = tid; i < 8 * DK; i += 256) {
    const int bh = bg * 8 + (i >> 7);
    const int d  = i & 127;
    const int b = bh >> 4, head = bh & 15;
    qv[i >> 7][d] = query[b * H_ + head * DK + d];
  }
  __syncthreads();
  const int j = jt * 256 + tid;
  const float bj = bias[j];
  float acc[8];
#pragma unroll
  for (int u = 0; u < 8; ++u) acc[u] = bj;
  for (int d = 0; d < DK; ++d) {
    const float wv = attn_w[d * H_ + j];
#pragma unroll
    for (int u = 0; u < 8; ++u) acc[u] += qv[u][d] * wv;
  }
#pragma unroll
  for (int u = 0; u < 8; ++u) qwb[(size_t)(bg * 8 + u) * H_ + j] = acc[u];
}

// ---------------------------------------------------------------------------
// Kernel 0b: Wk -> bf16 in MFMA fragment order:
// wktf[((nc*4+ks)*64 + lane)*8 + i] = Wk[k][n],
//   n = nc*16 + (lane&15), k = ks*32 + (lane>>4)*8 + i
// ---------------------------------------------------------------------------
__global__ void prep_wktf_kernel(const float* __restrict__ attn_w,
                                 __bf16* __restrict__ wktf) {
  const int t = blockIdx.x * blockDim.x + threadIdx.x;   // 0..32767
  const int lane  = t & 63;
  const int chunk = t >> 6;          // nc*4 + ks
  const int ks = chunk & 3;
  const int nc = chunk >> 2;
  const int row = lane & 15, g = lane >> 4;
  const int n  = nc * 16 + row;
  const int k0 = ks * 32 + g * 8;
  bf16x8 v;
#pragma unroll
  for (int i = 0; i < 8; ++i)
    v[i] = (__bf16)attn_w[(size_t)(DK + k0 + i) * H_ + n];
  *(bf16x8*)(wktf + (size_t)t * 8) = v;
}

// ---------------------------------------------------------------------------
// Kernel 1: logits[bh][l] = sum_n relu( (K Wk)[l][n] + qwb[bh][n] ) * score[n]
// Block = 4 waves x 64 rows = 256 rows of one bh. A resident in registers.
// B staged block-cooperatively via global_load_lds into a 4-slot x 8KB LDS
// ring (phase = 2 n-chunks). Counted s_waitcnt vmcnt(4) + RAW s_barrier per
// phase — loads stay in flight across barriers, no vmcnt(0) drain in-loop.
// ---------------------------------------------------------------------------
__global__ void __launch_bounds__(256, 2)
logits_kernel(const float* __restrict__ feed,
              const __bf16* __restrict__ wktf,
              const float* __restrict__ qwb,
              const float* __restrict__ score,
              float* __restrict__ logits) {
  const int ltile = blockIdx.x;     // 0..3 (256 rows each)
  const int bh    = blockIdx.y;     // 0..127
  const int b     = bh >> 4;
  const int head  = bh & 15;
  const int tid   = threadIdx.x;
  const int wave  = tid >> 6;
  const int lane  = tid & 63;
  const int row   = lane & 15;      // A row / B col / D col
  const int g     = lane >> 4;      // k-group 0..3

  __shared__ __bf16 ring[4 * 4096];    // 4 slots x 8KB (phase = 2 chunks)
  __shared__ float2 qs[H_];            // {qwb[bh][n], score[n]}: 16 KB

  // ---- stage qs (block-cooperative) ----
#pragma unroll
  for (int u = 0; u < 8; ++u) {
    const int n = tid + 256 * u;
    float2 t;
    t.x = qwb[(size_t)bh * H_ + n];
    t.y = score[n];
    qs[n] = t;
  }

  // ---- A fragments: 4 subtiles x 4 k-steps, resident in registers ----
  bf16x8 aF[4][4];
#pragma unroll
  for (int s = 0; s < 4; ++s) {
    const int l = ltile * 256 + wave * 64 + s * 16 + row;
    const float* fh = feed + (size_t)l * (B_ * H_) + b * H_ + head * DK;
#pragma unroll
    for (int ks = 0; ks < 4; ++ks) {
      const int k0 = ks * 32 + g * 8;
      float4 x = *(const float4*)(fh + k0);
      float4 y = *(const float4*)(fh + k0 + 4);
      bf16x8 t;
      t[0] = (__bf16)x.x; t[1] = (__bf16)x.y; t[2] = (__bf16)x.z; t[3] = (__bf16)x.w;
      t[4] = (__bf16)y.x; t[5] = (__bf16)y.y; t[6] = (__bf16)y.z; t[7] = (__bf16)y.w;
      aF[s][ks] = t;
    }
  }
  __syncthreads();   // qs visible to all waves; drains prologue loads (once)

  const char* wkb   = (const char*)wktf;
  char*       ringb = (char*)ring;
  const int   seg0  = wave * 2;      // this wave's two 1KB segments per phase

  // ---- issue ring prologue: phases 0,1 into slots 0,1 ----
#pragma unroll
  for (int ph = 0; ph < 2; ++ph) {
#pragma unroll
    for (int i = 0; i < 2; ++i)
      gload_lds16(wkb + (size_t)ph * 8192 + (seg0 + i) * 1024 + lane * 16,
                  ringb + ph * 8192 + (seg0 + i) * 1024);
  }

  float lacc[4][4] = {};

  for (int p = 0; p < 64; ++p) {
    // issue phase p+2 (clamped tail re-issues are harmless: they target the
    // slot that held phase p-2, whose reads finished before barrier p-1)
    const int pf = (p + 2 < 64) ? p + 2 : 63;
    const int ws = ((p + 2) & 3) * 8192;
    gload_lds16(wkb + (size_t)pf * 8192 + (seg0 + 0) * 1024 + lane * 16,
                ringb + ws + (seg0 + 0) * 1024);
    gload_lds16(wkb + (size_t)pf * 8192 + (seg0 + 1) * 1024 + lane * 16,
                ringb + ws + (seg0 + 1) * 1024);

    // own phase-p loads landed (leave p+1, p+2 = 4 loads in flight)
    asm volatile("s_waitcnt vmcnt(4)" ::: "memory");
    __builtin_amdgcn_s_barrier();        // all waves' phase-p loads landed
    __builtin_amdgcn_sched_barrier(0);

    const char* rs = ringb + (p & 3) * 8192;
#pragma unroll
    for (int cc = 0; cc < 2; ++cc) {
      bf16x8 bF[4];
#pragma unroll
      for (int ks = 0; ks < 4; ++ks)
        bF[ks] = *(const bf16x8*)(rs + cc * 4096 + ks * 1024 + lane * 16);
      const float2 q2 = qs[(2 * p + cc) * 16 + row];
      f32x4 d[4] = {{0.f,0.f,0.f,0.f},{0.f,0.f,0.f,0.f},
                    {0.f,0.f,0.f,0.f},{0.f,0.f,0.f,0.f}};
      __builtin_amdgcn_s_setprio(1);
#pragma unroll
      for (int ks = 0; ks < 4; ++ks) {
#pragma unroll
        for (int s = 0; s < 4; ++s)
          d[s] = __builtin_amdgcn_mfma_f32_16x16x32_bf16(aF[s][ks], bF[ks], d[s], 0, 0, 0);
      }
      __builtin_amdgcn_s_setprio(0);
#pragma unroll
      for (int s = 0; s < 4; ++s) {
#pragma unroll
        for (int i = 0; i < 4; ++i)
          lacc[s][i] += fmaxf(d[s][i] + q2.x, 0.f) * q2.y;
      }
    }
  }

  // ---- reduce over the 16 D-columns, write logits ----
#pragma unroll
  for (int s = 0; s < 4; ++s) {
#pragma unroll
    for (int i = 0; i < 4; ++i) {
      float v = lacc[s][i];
#pragma unroll
      for (int off = 1; off < 16; off <<= 1) v += __shfl_xor(v, off);
      lacc[s][i] = v;
    }
  }
  if (row == 0) {
#pragma unroll
    for (int s = 0; s < 4; ++s) {
      const int base = bh * L_ + ltile * 256 + wave * 64 + s * 16 + g * 4;
#pragma unroll
      for (int i = 0; i < 4; ++i) logits[base + i] = lacc[s][i];
    }
  }
}

// ---------------------------------------------------------------------------
// Kernel 2: grid (bh, dpart): softmax over L (redundant per dpart, cheap),
// then out[d] over this block's 32 d-columns. values read as float4.
// ---------------------------------------------------------------------------
__global__ void __launch_bounds__(256)
softmax_pv_kernel(const float* __restrict__ logits,
                  const float* __restrict__ values,
                  float* __restrict__ out) {
  const int bh    = blockIdx.x;   // 0..127
  const int dpart = blockIdx.y;   // 0..3  (32 d-cols each)
  const int b     = bh >> 4;
  const int head  = bh & 15;
  const int tid   = threadIdx.x;

  __shared__ float  sl[L_];
  __shared__ float  sred[4];
  __shared__ float  sscal;
  __shared__ float4 pacc[32][8];

  float m = -1e30f;
  for (int i = tid; i < L_; i += 256) {
    float v = logits[(size_t)bh * L_ + i];
    sl[i] = v;
    m = fmaxf(m, v);
  }
#pragma unroll
  for (int off = 32; off > 0; off >>= 1) m = fmaxf(m, __shfl_xor(m, off));
  if ((tid & 63) == 0) sred[tid >> 6] = m;
  __syncthreads();
  if (tid == 0) {
    float mm = fmaxf(fmaxf(sred[0], sred[1]), fmaxf(sred[2], sred[3]));
    sscal = mm;
  }
  __syncthreads();
  const float mx = sscal;

  float s = 0.f;
  for (int i = tid; i < L_; i += 256) {
    float e = __expf(sl[i] - mx);
    sl[i] = e;
    s += e;
  }
#pragma unroll
  for (int off = 32; off > 0; off >>= 1) s += __shfl_xor(s, off);
  if ((tid & 63) == 0) sred[tid >> 6] = s;
  __syncthreads();
  if (tid == 0) {
    sscal = 1.0f / ((sred[0] + sred[1]) + (sred[2] + sred[3]));
  }
  __syncthreads();
  const float inv = sscal;

  // PV over 32 cols: 8 float4-cols x 32 l-subsets
  const int dq4  = tid & 7;
  const int lsub = tid >> 3;
  const float4* vp = (const float4*)(values + (size_t)b * H_ + head * DK + dpart * 32) + dq4;
  float4 acc = {0.f, 0.f, 0.f, 0.f};
  for (int ll = lsub; ll < L_; ll += 32) {
    const float w = sl[ll];
    float4 v = vp[(size_t)ll * (B_ * H_ / 4)];
    acc.x += w * v.x; acc.y += w * v.y; acc.z += w * v.z; acc.w += w * v.w;
  }
  pacc[lsub][dq4] = acc;
  __syncthreads();
  if (tid < 64) {
    const int q = tid & 7, k = tid >> 3;
    float4 a0 = pacc[k][q], a1 = pacc[k + 8][q], a2 = pacc[k + 16][q], a3 = pacc[k + 24][q];
    float4 r;
    r.x = (a0.x + a1.x) + (a2.x + a3.x);
    r.y = (a0.y + a1.y) + (a2.y + a3.y);
    r.z = (a0.z + a1.z) + (a2.z + a3.z);
    r.w = (a0.w + a1.w) + (a2.w + a3.w);
    pacc[k][q] = r;
  }
  __syncthreads();
  if (tid < 8) {
    float4 t = {0.f, 0.f, 0.f, 0.f};
#pragma unroll
    for (int k = 0; k < 8; ++k) {
      float4 a = pacc[k][tid];
      t.x += a.x; t.y += a.y; t.z += a.z; t.w += a.w;
    }
    t.x *= inv; t.y *= inv; t.z *= inv; t.w *= inv;
    *(float4*)(out + (size_t)b * H_ + head * DK + dpart * 32 + tid * 4) = t;
  }
}

// ---------------------------------------------------------------------------
extern "C" void kernel_launch(void* const* d_in, const int* in_sizes, int n_in,
                              void* d_out, int out_size, void* d_ws, size_t ws_size,
                              hipStream_t stream) {
  const float* query  = (const float*)d_in[0];
  const float* feed   = (const float*)d_in[1];
  const float* values = (const float*)d_in[2];
  const float* attn_w = (const float*)d_in[3];
  const float* bias   = (const float*)d_in[4];
  const float* score  = (const float*)d_in[5];
  float* out = (float*)d_out;

  // Workspace: qwb (1 MB f32) | wktf (512 KB bf16) | logits (512 KB f32)
  float*  qwb    = (float*)d_ws;
  __bf16* wktf   = (__bf16*)((char*)d_ws + (size_t)(B_ * HEADS * H_) * sizeof(float));
  float*  logits = (float*)((char*)wktf + (size_t)(H_ * DK) * sizeof(__bf16));

  prep_qwb_kernel<<<dim3(H_ / 256, B_ * HEADS / 8), 256, 0, stream>>>(query, attn_w, bias, qwb);
  prep_wktf_kernel<<<(H_ * DK / 8) / 256, 256, 0, stream>>>(attn_w, wktf);
  logits_kernel<<<dim3(L_ / 256, B_ * HEADS), 256, 0, stream>>>(feed, wktf, qwb, score, logits);
  softmax_pv_kernel<<<dim3(B_ * HEADS, 4), 256, 0, stream>>>(logits, values, out);
}